// Round 7
// baseline (1103.192 us; speedup 1.0000x reference)
//
#include <hip/hip_runtime.h>

// ---------------------------------------------------------------------------
// ASA (AdaAttN-style) fused pipeline for MI355X / gfx950
// B=4, C=256, H=W=64 -> N=M=4096 tokens.
//
// R7: occupancy + VALU cuts on the R6 structure.
//  * k_flash: c-split 8 (32 ch/block), m-tile 32 -> LDS 33792 B ->
//    4 blocks/CU x 4 waves = 16 waves/CU (4/SIMD), grid 1024 blocks
//  * raw v_exp_f32 (__builtin_amdgcn_exp2f) instead of exp2f libcall
//  * alpha broadcast via __shfl (no LDS round-trip)
//  * prefix: 1 k_prep launch (3 transposes + wcvt; ckey staged into d_out
//    scratch), Q+K GEMMs in one launch (Q: scratch->A, K: in-place)
//
//  ws + 0        : cm   [1024] f32
//  ws + 4096     : cr   [1024] f32
//  ws + 8192     : Wb   [3*65536] fp16
//  ws + 1 MiB    : A    8 MiB  fp16   Xs -> Qt
//  ws + 9 MiB    : Bv   8 MiB  fp16   Vt [c][tok]
//  ws + 17 MiB   : Cc   8 MiB  fp16   Xk -> Kt (in-place)
//  d_out (16 MB) : Xq scratch (dead before k_flash writes out)
// ---------------------------------------------------------------------------

typedef unsigned int u32;
typedef unsigned short u16;
typedef _Float16 f16x8 __attribute__((ext_vector_type(8)));
typedef float f32x4 __attribute__((ext_vector_type(4)));
typedef float f32x16 __attribute__((ext_vector_type(16)));

#define L2E 1.44269504088896340736f
#define MFMA(a, b, c) __builtin_amdgcn_mfma_f32_16x16x32_f16(a, b, c, 0, 0, 0)
#define MFMA32(a, b, c) __builtin_amdgcn_mfma_f32_32x32x16_f16(a, b, c, 0, 0, 0)
#define EXP2(x) __builtin_amdgcn_exp2f(x)

__device__ __forceinline__ u16 h_bits(_Float16 h) { return __builtin_bit_cast(u16, h); }
__device__ __forceinline__ _Float16 bits_h(u16 x) { return __builtin_bit_cast(_Float16, x); }
__device__ __forceinline__ u16 f2h(float f) { return h_bits((_Float16)f); }

__device__ __forceinline__ f16x8 ldh8(const u16* p) {
    uint4 v = *(const uint4*)p;
    return __builtin_bit_cast(f16x8, v);
}

// ---------------- content stats: mean & rstd per (b,c) ---------------------
__global__ void k_stats(const float* __restrict__ content,
                        float* __restrict__ cm, float* __restrict__ cr) {
    int blk = blockIdx.x;                       // 0..1023 = b*256+c
    const float* p = content + (size_t)blk * 4096;
    int t = threadIdx.x;
    float s = 0.f, ss = 0.f;
    for (int i = 0; i < 4; i++) {
        float4 v = *(const float4*)(p + (i * 256 + t) * 4);
        s  += (v.x + v.y) + (v.z + v.w);
        ss += (v.x * v.x + v.y * v.y) + (v.z * v.z + v.w * v.w);
    }
    for (int d = 32; d >= 1; d >>= 1) { s += __shfl_xor(s, d); ss += __shfl_xor(ss, d); }
    __shared__ __align__(16) float as[4], ass[4];
    int w = t >> 6;
    if ((t & 63) == 0) { as[w] = s; ass[w] = ss; }
    __syncthreads();
    if (t == 0) {
        s  = (as[0] + as[1]) + (as[2] + as[3]);
        ss = (ass[0] + ass[1]) + (ass[2] + ass[3]);
        float mean = s * (1.0f / 4096.0f);
        float var = (ss - s * mean) * (1.0f / 4095.0f);   // unbiased (ddof=1)
        cm[blk] = mean;
        cr[blk] = rsqrtf(var + 1e-5f);
    }
}

// ---------------- prep: 3 transposes + weight cvt in ONE launch ------------
// z 0..3: style->A ; 4..7: ckey->Xq(out scratch) ; 8..11: skey->Cc ;
// z 12..14: W(z-12) fp32->fp16 (y==0 blocks only)
__global__ void k_prep(const float* __restrict__ style, const float* __restrict__ ckey,
                       const float* __restrict__ skey,
                       const float* __restrict__ Wf, const float* __restrict__ Wg,
                       const float* __restrict__ Wh,
                       u16* __restrict__ A, u16* __restrict__ Xq, u16* __restrict__ Cc,
                       u16* __restrict__ Wb) {
    int z = blockIdx.z, t = threadIdx.x;
    if (z >= 12) {
        if (blockIdx.y != 0) return;
        int m = z - 12;
        const float* src = (m == 0) ? Wf : ((m == 1) ? Wg : Wh);
        u16* dst = Wb + m * 65536;
        int i = (blockIdx.x * 256 + t) * 4;
        float4 v = *(const float4*)(src + i);
        ushort4 o;
        o.x = f2h(v.x); o.y = f2h(v.y); o.z = f2h(v.z); o.w = f2h(v.w);
        *(ushort4*)(dst + i) = o;
        return;
    }
    int tensor = z >> 2, b = z & 3;
    const float* src = ((tensor == 0) ? style : ((tensor == 1) ? ckey : skey))
                       + (size_t)b * 256 * 4096;
    u16* dst = ((tensor == 0) ? A : ((tensor == 1) ? Xq : Cc)) + (size_t)b * 4096 * 256;
    int c0 = blockIdx.y * 64, t0 = blockIdx.x * 64;
    __shared__ __align__(16) float ls[64][65];
    int tr = t >> 4, tc = t & 15;
    for (int i = 0; i < 4; i++) {
        int c_off = i * 16 + tr;
        float4 v = *(const float4*)(src + (size_t)(c0 + c_off) * 4096 + t0 + tc * 4);
        ls[tc * 4 + 0][c_off] = v.x;
        ls[tc * 4 + 1][c_off] = v.y;
        ls[tc * 4 + 2][c_off] = v.z;
        ls[tc * 4 + 3][c_off] = v.w;
    }
    __syncthreads();
    for (int i = 0; i < 4; i++) {
        int tokrow = i * 16 + tr;
        ushort4 o;
        o.x = f2h(ls[tokrow][tc * 4 + 0]);
        o.y = f2h(ls[tokrow][tc * 4 + 1]);
        o.z = f2h(ls[tokrow][tc * 4 + 2]);
        o.w = f2h(ls[tokrow][tc * 4 + 3]);
        *(ushort4*)(dst + (size_t)(t0 + tokrow) * 256 + c0 + tc * 4) = o;
    }
}

// ---------------- Q/K conv1x1 GEMM -----------------------------------------
// mode 0: Q[tok][o] = Xq*Wf^T + bf   (Xq in out-scratch -> write A)
// mode 1: K[tok][o] = Xk*Wg^T + bg   (in-place in Cc)
__launch_bounds__(256, 2)
__global__ void k_gemm_qk(const u16* Xqs, u16* Qd, u16* Xk, const u16* __restrict__ Wb,
                          const float* __restrict__ bfp, const float* __restrict__ bgp) {
    int mode = blockIdx.z, b = blockIdx.y, tok0 = blockIdx.x * 128;
    const u16* X = ((mode == 0) ? Xqs : Xk) + (size_t)b * 4096 * 256;
    u16* O = ((mode == 0) ? Qd : Xk) + (size_t)b * 4096 * 256;
    const u16* W = Wb + mode * 65536;
    const float* bias = (mode == 0) ? bfp : bgp;
    __shared__ __align__(16) u16 wt[256 * 40];
    int t = threadIdx.x, w = t >> 6, lane = t & 63, ln = lane & 15, quad = lane >> 4;

    f32x4 acc[8][4];
    for (int i = 0; i < 8; i++)
        for (int j = 0; j < 4; j++) acc[i][j] = f32x4{0.f, 0.f, 0.f, 0.f};

    for (int ks = 0; ks < 8; ks++) {
        {   // stage W[o = t][ks*32 .. +32) -> LDS : full 64 B per row
            const u16* wr = W + t * 256 + ks * 32;
            uint4 w0 = *(const uint4*)(wr + 0);
            uint4 w1 = *(const uint4*)(wr + 8);
            uint4 w2 = *(const uint4*)(wr + 16);
            uint4 w3 = *(const uint4*)(wr + 24);
            *(uint4*)(wt + t * 40 + 0)  = w0;
            *(uint4*)(wt + t * 40 + 8)  = w1;
            *(uint4*)(wt + t * 40 + 16) = w2;
            *(uint4*)(wt + t * 40 + 24) = w3;
        }
        __syncthreads();
        f16x8 wf[4];
        #pragma unroll
        for (int ct = 0; ct < 4; ct++)
            wf[ct] = ldh8(wt + (w * 64 + ct * 16 + ln) * 40 + quad * 8);
        #pragma unroll
        for (int rt = 0; rt < 8; rt++) {
            f16x8 xf = ldh8(X + (size_t)(tok0 + rt * 16 + ln) * 256 + ks * 32 + quad * 8);
            #pragma unroll
            for (int ct = 0; ct < 4; ct++) acc[rt][ct] = MFMA(xf, wf[ct], acc[rt][ct]);
        }
        __syncthreads();
    }

    float bv[4];
    #pragma unroll
    for (int ct = 0; ct < 4; ct++) bv[ct] = bias[w * 64 + ct * 16 + ln];
    #pragma unroll
    for (int rt = 0; rt < 8; rt++)
        #pragma unroll
        for (int ct = 0; ct < 4; ct++)
            #pragma unroll
            for (int r = 0; r < 4; r++) {
                int tok = tok0 + rt * 16 + quad * 4 + r;
                int o = w * 64 + ct * 16 + ln;
                O[(size_t)tok * 256 + o] = f2h(acc[rt][ct][r] + bv[ct]);
            }
}

// ---------------- V conv1x1 GEMM: Xs -> V[o][tok] channel-major ------------
__launch_bounds__(256, 2)
__global__ void k_gemm_v(const u16* Xs, const u16* __restrict__ Wh2,
                         const float* __restrict__ bhp, u16* Vt) {
    int b = blockIdx.y, tok0 = blockIdx.x * 128;
    const u16* X = Xs + (size_t)b * 4096 * 256;
    __shared__ __align__(16) u16 wt[256 * 40];
    int t = threadIdx.x, w = t >> 6, lane = t & 63, ln = lane & 15, quad = lane >> 4;

    f32x4 acc[8][4];
    for (int i = 0; i < 8; i++)
        for (int j = 0; j < 4; j++) acc[i][j] = f32x4{0.f, 0.f, 0.f, 0.f};

    for (int ks = 0; ks < 8; ks++) {
        {
            const u16* wr = Wh2 + t * 256 + ks * 32;
            uint4 w0 = *(const uint4*)(wr + 0);
            uint4 w1 = *(const uint4*)(wr + 8);
            uint4 w2 = *(const uint4*)(wr + 16);
            uint4 w3 = *(const uint4*)(wr + 24);
            *(uint4*)(wt + t * 40 + 0)  = w0;
            *(uint4*)(wt + t * 40 + 8)  = w1;
            *(uint4*)(wt + t * 40 + 16) = w2;
            *(uint4*)(wt + t * 40 + 24) = w3;
        }
        __syncthreads();
        f16x8 wf[4];
        #pragma unroll
        for (int ct = 0; ct < 4; ct++)
            wf[ct] = ldh8(wt + (w * 64 + ct * 16 + ln) * 40 + quad * 8);
        #pragma unroll
        for (int rt = 0; rt < 8; rt++) {
            f16x8 xf = ldh8(X + (size_t)(tok0 + rt * 16 + ln) * 256 + ks * 32 + quad * 8);
            #pragma unroll
            for (int ct = 0; ct < 4; ct++) acc[rt][ct] = MFMA(wf[ct], xf, acc[rt][ct]);
        }
        __syncthreads();
    }

    u16* OV = Vt + (size_t)b * 256 * 4096;
    #pragma unroll
    for (int ct = 0; ct < 4; ct++)
        #pragma unroll
        for (int r = 0; r < 4; r++) {
            int o = w * 64 + ct * 16 + quad * 4 + r;
            float bb = bhp[o];
            #pragma unroll
            for (int rt = 0; rt < 8; rt++) {
                int tok = tok0 + rt * 16 + ln;
                OV[(size_t)o * 4096 + tok] = f2h(acc[rt][ct][r] + bb);
            }
        }
}

// ---------------- flash attention + fused AdaIN epilogue -------------------
// grid: (32 q-tiles of 128, 4 batch, 8 c-eighths) = 1024 blocks -> 4/CU
// (LDS 33792 B/block), 16 waves/CU = 4/SIMD. Wave owns 32 q-rows; m-tile 32.
// S^T = K*Q^T (32x32x16); softmax in-lane + one shfl_xor(32); alpha via shfl.
__launch_bounds__(256, 4)
__global__ void k_flash(const u16* __restrict__ Qt, const u16* __restrict__ Kt,
                        const u16* __restrict__ Vt,
                        const float* __restrict__ content, const float* __restrict__ cm,
                        const float* __restrict__ cr, float* __restrict__ out) {
    __shared__ __align__(16) char smem[33792];
    u16* Ks = (u16*)smem;                    // [32 tok][264]  16896 B
    u16* Vc = (u16*)(smem + 16896);          // [32 c][104]: V | V2h(+32) | V2l(+64)
    int t = threadIdx.x, w = t >> 6, l = t & 63, lq = l & 31, h = l >> 5;
    u16* Psw = (u16*)(smem + 23552) + w * 1280;   // per-wave [32 q][40 m]

    int b = blockIdx.y, q0 = blockIdx.x * 128, coff = blockIdx.z * 32;

    // Q as B-operand fragments, pinned: col q = lq, k = h*8+j (+16ks)
    f16x8 qf[16];
    {
        const u16* qp = Qt + ((size_t)b * 4096 + q0 + w * 32 + lq) * 256 + h * 8;
        #pragma unroll
        for (int ks = 0; ks < 16; ks++) qf[ks] = ldh8(qp + ks * 16);
    }

    f32x16 am, aq;
    #pragma unroll
    for (int i = 0; i < 16; i++) { am[i] = 0.f; aq[i] = 0.f; }
    float mrow = -1e30f, lrow = 0.f;

    const u16* Kg = Kt + (size_t)b * 4096 * 256;
    const u16* Vg = Vt + ((size_t)b * 256 + coff) * 4096;

    for (int it = 0; it < 128; it++) {
        int m0 = it * 32;
        // stage K tile [32 tok][256 c]: 4 uint4/thread
        #pragma unroll
        for (int i = 0; i < 4; i++) {
            int e = i * 256 + t, row = e >> 5, c16 = e & 31;
            *(uint4*)(Ks + row * 264 + c16 * 8) =
                *(const uint4*)(Kg + (size_t)(m0 + row) * 256 + c16 * 8);
        }
        // stage V tile [32 c][32 m] + exact hi/lo fp16 split of v^2
        if (t < 128) {
            int row = t >> 2, m16 = t & 3;
            uint4 v = *(const uint4*)(Vg + (size_t)row * 4096 + m0 + m16 * 8);
            *(uint4*)(Vc + row * 104 + m16 * 8) = v;
            uint4 qh, ql;
            u32* vp = (u32*)&v; u32* hp = (u32*)&qh; u32* lp = (u32*)&ql;
            #pragma unroll
            for (int j = 0; j < 4; j++) {
                u32 x = vp[j];
                float v0 = (float)bits_h((u16)(x & 0xFFFFu));
                float v1 = (float)bits_h((u16)(x >> 16));
                float s0 = v0 * v0, s1 = v1 * v1;          // exact in fp32
                u16 h0 = f2h(s0), h1 = f2h(s1);
                float l0 = s0 - (float)bits_h(h0);         // exact remainder
                float l1 = s1 - (float)bits_h(h1);
                hp[j] = (u32)h0 | ((u32)h1 << 16);
                lp[j] = (u32)f2h(l0) | ((u32)f2h(l1) << 16);
            }
            *(uint4*)(Vc + row * 104 + 32 + m16 * 8) = qh;
            *(uint4*)(Vc + row * 104 + 64 + m16 * 8) = ql;
        }
        __syncthreads();

        // S^T[m][q] = K * Q^T
        f32x16 s;
        #pragma unroll
        for (int i = 0; i < 16; i++) s[i] = 0.f;
        #pragma unroll
        for (int ks = 0; ks < 16; ks++) {
            f16x8 kf = ldh8(Ks + lq * 264 + ks * 16 + h * 8);
            s = MFMA32(kf, qf[ks], s);
        }

        // online softmax over m: in-lane (16 vals) + one shfl_xor(32)
        float mt = s[0];
        #pragma unroll
        for (int r = 1; r < 16; r++) mt = fmaxf(mt, s[r]);
        mt = fmaxf(mt, __shfl_xor(mt, 32));
        float mn = fmaxf(mrow, mt);
        float al = EXP2((mrow - mn) * L2E);
        mrow = mn;
        float base = mn * L2E;
        float rs = 0.f;
        #pragma unroll
        for (int r = 0; r < 16; r++) {
            float p = (float)(_Float16)EXP2(__builtin_fmaf(s[r], L2E, -base));
            s[r] = p;
            rs += p;
        }
        rs += __shfl_xor(rs, 32);
        lrow = lrow * al + rs;

        // rescale accumulators; alpha of q broadcast via shfl (lane q holds it)
        #pragma unroll
        for (int r = 0; r < 16; r++) {
            float sc = __shfl(al, 8 * (r >> 2) + 4 * h + (r & 3));
            am[r] *= sc; aq[r] *= sc;
        }

        // P -> Psw[q = lq][m], packed 4 consecutive m per b64 write
        #pragma unroll
        for (int rq = 0; rq < 4; rq++) {
            uint2 pk;
            pk.x = (u32)f2h(s[4 * rq + 0]) | ((u32)f2h(s[4 * rq + 1]) << 16);
            pk.y = (u32)f2h(s[4 * rq + 2]) | ((u32)f2h(s[4 * rq + 3]) << 16);
            *(uint2*)(Psw + lq * 40 + rq * 8 + h * 4) = pk;   // m = 8rq+4h+j
        }

        // PV: D[q][c] += P*V (am), P*V2h + P*V2l (aq); same-wave LDS RAW
        #pragma unroll
        for (int ks = 0; ks < 2; ks++) {
            f16x8 pf = ldh8(Psw + lq * 40 + ks * 16 + h * 8);
            int vo = lq * 104 + ks * 16 + h * 8;
            am = MFMA32(pf, ldh8(Vc + vo), am);
            aq = MFMA32(pf, ldh8(Vc + vo + 32), aq);
            aq = MFMA32(pf, ldh8(Vc + vo + 64), aq);
        }
        __syncthreads();
    }

    // ---------------- epilogue: out = std * norm(content) + mean ----------
    float inv = 1.0f / lrow;
    float iv[16];
    #pragma unroll
    for (int r = 0; r < 16; r++) iv[r] = __shfl(inv, 8 * (r >> 2) + 4 * h + (r & 3));
    float* Ms = (float*)smem;                  // [32 c][132 q] f32  (overlays loop LDS)
    float* Ss = (float*)(smem + 16896);
    #pragma unroll
    for (int rq = 0; rq < 4; rq++) {
        f32x4 mv, sv;
        #pragma unroll
        for (int j = 0; j < 4; j++) {
            int r = 4 * rq + j;
            float mean = am[r] * iv[r];
            float ex2 = aq[r] * iv[r];
            float var = ex2 - mean * mean;
            mv[j] = mean;
            sv[j] = sqrtf(fmaxf(var, 0.f));
        }
        int qloc = w * 32 + 8 * rq + 4 * h;
        *(f32x4*)(Ms + lq * 132 + qloc) = mv;
        *(f32x4*)(Ss + lq * 132 + qloc) = sv;
    }
    __syncthreads();
    #pragma unroll
    for (int i = 0; i < 4; i++) {
        int cl = i * 8 + (t >> 5);
        int qloc = (t & 31) * 4;
        f32x4 mv = *(const f32x4*)(Ms + cl * 132 + qloc);
        f32x4 sv = *(const f32x4*)(Ss + cl * 132 + qloc);
        int gc = coff + cl;
        size_t basei = ((size_t)b * 256 + gc) * 4096 + q0 + qloc;
        float4 cv = *(const float4*)(content + basei);
        float cmv = cm[b * 256 + gc], crv = cr[b * 256 + gc];
        float4 o;
        o.x = sv[0] * ((cv.x - cmv) * crv) + mv[0];
        o.y = sv[1] * ((cv.y - cmv) * crv) + mv[1];
        o.z = sv[2] * ((cv.z - cmv) * crv) + mv[2];
        o.w = sv[3] * ((cv.w - cmv) * crv) + mv[3];
        *(float4*)(out + basei) = o;
    }
}

// ---------------------------------------------------------------------------
extern "C" void kernel_launch(void* const* d_in, const int* in_sizes, int n_in,
                              void* d_out, int out_size, void* d_ws, size_t ws_size,
                              hipStream_t stream) {
    const float* content = (const float*)d_in[0];
    const float* style   = (const float*)d_in[1];
    const float* ckey    = (const float*)d_in[2];
    const float* skey    = (const float*)d_in[3];
    const float* Wf      = (const float*)d_in[4];
    const float* bfp     = (const float*)d_in[5];
    const float* Wg      = (const float*)d_in[6];
    const float* bgp     = (const float*)d_in[7];
    const float* Wh      = (const float*)d_in[8];
    const float* bhp     = (const float*)d_in[9];
    float* out = (float*)d_out;
    char* ws = (char*)d_ws;

    float* cm = (float*)(ws + 0);               //  4 KiB
    float* cr = (float*)(ws + 4096);            //  4 KiB
    u16*   Wb = (u16*)(ws + 8192);              //  384 KiB
    u16*   A  = (u16*)(ws + 1048576);           //  8 MiB: Xs -> Qt
    u16*   Bv = (u16*)(ws + 9437184);           //  8 MiB: Vt [c][tok]
    u16*   Cc = (u16*)(ws + 17825792);          //  8 MiB: Xk -> Kt
    u16*   Xq = (u16*)d_out;                    //  8 MiB scratch inside out (16 MB)

    k_stats<<<dim3(1024), 256, 0, stream>>>(content, cm, cr);
    k_prep<<<dim3(64, 4, 15), 256, 0, stream>>>(style, ckey, skey, Wf, Wg, Wh,
                                                A, Xq, Cc, Wb);
    k_gemm_v<<<dim3(32, 4), 256, 0, stream>>>(A, Wb + 2 * 65536, bhp, Bv);
    k_gemm_qk<<<dim3(32, 4, 2), 256, 0, stream>>>(Xq, A, Cc, Wb, bfp, bgp);
    k_flash<<<dim3(32, 4, 8), 256, 0, stream>>>(A, Cc, Bv, content, cm, cr, out);
}

// Round 8
// 420.877 us; speedup vs baseline: 2.6212x; 2.6212x over previous
//
#include <hip/hip_runtime.h>

// ---------------------------------------------------------------------------
// ASA (AdaAttN-style) fused pipeline for MI355X / gfx950
// B=4, C=256, H=W=64 -> N=M=4096 tokens.
//
// R8: R7 regressed 3x (FETCH 95MB -> 3.0GB): 4 blocks/CU + 32-row m-tiles +
// 8-way c-split destroyed inter-block K-tile locality in L2. Revert to the
// R6 flash structure (512 blocks, 64-row tiles, c-split 4 -> FETCH ~95MB)
// and keep only R7's orthogonal wins:
//  * raw v_exp_f32 (EXP2) instead of exp2f libcall  (~half of R6's VALU)
//  * alpha broadcast via __shfl (no LDS round-trip)
//  * packed-f16 Dekker split for V^2 (exact, 8 pk-ops vs ~140 scalar)
//  * consolidated prefix (k_prep; Q+K GEMM one launch; Xq scratch in d_out)
//
//  ws + 0      : cm [1024] f32      ws + 4096  : cr [1024] f32
//  ws + 8192   : Wb [3*65536] fp16
//  ws + 1 MiB  : A  8 MiB fp16  Xs -> Qt
//  ws + 9 MiB  : Bv 8 MiB fp16  Vt [c][tok]
//  ws + 17 MiB : Cc 8 MiB fp16  Xk -> Kt (in-place)
//  d_out       : Xq scratch (dead before k_flash writes out)
// ---------------------------------------------------------------------------

typedef unsigned int u32;
typedef unsigned short u16;
typedef _Float16 f16x8 __attribute__((ext_vector_type(8)));
typedef float f32x4 __attribute__((ext_vector_type(4)));
typedef float f32x16 __attribute__((ext_vector_type(16)));

#define L2E 1.44269504088896340736f
#define MFMA(a, b, c) __builtin_amdgcn_mfma_f32_16x16x32_f16(a, b, c, 0, 0, 0)
#define MFMA32(a, b, c) __builtin_amdgcn_mfma_f32_32x32x16_f16(a, b, c, 0, 0, 0)
#define EXP2(x) __builtin_amdgcn_exp2f(x)

__device__ __forceinline__ u16 h_bits(_Float16 h) { return __builtin_bit_cast(u16, h); }
__device__ __forceinline__ _Float16 bits_h(u16 x) { return __builtin_bit_cast(_Float16, x); }
__device__ __forceinline__ u16 f2h(float f) { return h_bits((_Float16)f); }

__device__ __forceinline__ f16x8 ldh8(const u16* p) {
    uint4 v = *(const uint4*)p;
    return __builtin_bit_cast(f16x8, v);
}

// ---------------- content stats: mean & rstd per (b,c) ---------------------
__global__ void k_stats(const float* __restrict__ content,
                        float* __restrict__ cm, float* __restrict__ cr) {
    int blk = blockIdx.x;                       // 0..1023 = b*256+c
    const float* p = content + (size_t)blk * 4096;
    int t = threadIdx.x;
    float s = 0.f, ss = 0.f;
    for (int i = 0; i < 4; i++) {
        float4 v = *(const float4*)(p + (i * 256 + t) * 4);
        s  += (v.x + v.y) + (v.z + v.w);
        ss += (v.x * v.x + v.y * v.y) + (v.z * v.z + v.w * v.w);
    }
    for (int d = 32; d >= 1; d >>= 1) { s += __shfl_xor(s, d); ss += __shfl_xor(ss, d); }
    __shared__ __align__(16) float as[4], ass[4];
    int w = t >> 6;
    if ((t & 63) == 0) { as[w] = s; ass[w] = ss; }
    __syncthreads();
    if (t == 0) {
        s  = (as[0] + as[1]) + (as[2] + as[3]);
        ss = (ass[0] + ass[1]) + (ass[2] + ass[3]);
        float mean = s * (1.0f / 4096.0f);
        float var = (ss - s * mean) * (1.0f / 4095.0f);   // unbiased (ddof=1)
        cm[blk] = mean;
        cr[blk] = rsqrtf(var + 1e-5f);
    }
}

// ---------------- prep: 3 transposes + weight cvt in ONE launch ------------
__global__ void k_prep(const float* __restrict__ style, const float* __restrict__ ckey,
                       const float* __restrict__ skey,
                       const float* __restrict__ Wf, const float* __restrict__ Wg,
                       const float* __restrict__ Wh,
                       u16* __restrict__ A, u16* __restrict__ Xq, u16* __restrict__ Cc,
                       u16* __restrict__ Wb) {
    int z = blockIdx.z, t = threadIdx.x;
    if (z >= 12) {
        if (blockIdx.y != 0) return;
        int m = z - 12;
        const float* src = (m == 0) ? Wf : ((m == 1) ? Wg : Wh);
        u16* dst = Wb + m * 65536;
        int i = (blockIdx.x * 256 + t) * 4;
        float4 v = *(const float4*)(src + i);
        ushort4 o;
        o.x = f2h(v.x); o.y = f2h(v.y); o.z = f2h(v.z); o.w = f2h(v.w);
        *(ushort4*)(dst + i) = o;
        return;
    }
    int tensor = z >> 2, b = z & 3;
    const float* src = ((tensor == 0) ? style : ((tensor == 1) ? ckey : skey))
                       + (size_t)b * 256 * 4096;
    u16* dst = ((tensor == 0) ? A : ((tensor == 1) ? Xq : Cc)) + (size_t)b * 4096 * 256;
    int c0 = blockIdx.y * 64, t0 = blockIdx.x * 64;
    __shared__ __align__(16) float ls[64][65];
    int tr = t >> 4, tc = t & 15;
    for (int i = 0; i < 4; i++) {
        int c_off = i * 16 + tr;
        float4 v = *(const float4*)(src + (size_t)(c0 + c_off) * 4096 + t0 + tc * 4);
        ls[tc * 4 + 0][c_off] = v.x;
        ls[tc * 4 + 1][c_off] = v.y;
        ls[tc * 4 + 2][c_off] = v.z;
        ls[tc * 4 + 3][c_off] = v.w;
    }
    __syncthreads();
    for (int i = 0; i < 4; i++) {
        int tokrow = i * 16 + tr;
        ushort4 o;
        o.x = f2h(ls[tokrow][tc * 4 + 0]);
        o.y = f2h(ls[tokrow][tc * 4 + 1]);
        o.z = f2h(ls[tokrow][tc * 4 + 2]);
        o.w = f2h(ls[tokrow][tc * 4 + 3]);
        *(ushort4*)(dst + (size_t)(t0 + tokrow) * 256 + c0 + tc * 4) = o;
    }
}

// ---------------- Q/K conv1x1 GEMM -----------------------------------------
// mode 0: Q = Xq(out scratch)*Wf^T + bf -> A ; mode 1: K in-place in Cc
__launch_bounds__(256, 2)
__global__ void k_gemm_qk(const u16* Xqs, u16* Qd, u16* Xk, const u16* __restrict__ Wb,
                          const float* __restrict__ bfp, const float* __restrict__ bgp) {
    int mode = blockIdx.z, b = blockIdx.y, tok0 = blockIdx.x * 128;
    const u16* X = ((mode == 0) ? Xqs : Xk) + (size_t)b * 4096 * 256;
    u16* O = ((mode == 0) ? Qd : Xk) + (size_t)b * 4096 * 256;
    const u16* W = Wb + mode * 65536;
    const float* bias = (mode == 0) ? bfp : bgp;
    __shared__ __align__(16) u16 wt[256 * 40];
    int t = threadIdx.x, w = t >> 6, lane = t & 63, ln = lane & 15, quad = lane >> 4;

    f32x4 acc[8][4];
    for (int i = 0; i < 8; i++)
        for (int j = 0; j < 4; j++) acc[i][j] = f32x4{0.f, 0.f, 0.f, 0.f};

    for (int ks = 0; ks < 8; ks++) {
        {
            const u16* wr = W + t * 256 + ks * 32;
            uint4 w0 = *(const uint4*)(wr + 0);
            uint4 w1 = *(const uint4*)(wr + 8);
            uint4 w2 = *(const uint4*)(wr + 16);
            uint4 w3 = *(const uint4*)(wr + 24);
            *(uint4*)(wt + t * 40 + 0)  = w0;
            *(uint4*)(wt + t * 40 + 8)  = w1;
            *(uint4*)(wt + t * 40 + 16) = w2;
            *(uint4*)(wt + t * 40 + 24) = w3;
        }
        __syncthreads();
        f16x8 wf[4];
        #pragma unroll
        for (int ct = 0; ct < 4; ct++)
            wf[ct] = ldh8(wt + (w * 64 + ct * 16 + ln) * 40 + quad * 8);
        #pragma unroll
        for (int rt = 0; rt < 8; rt++) {
            f16x8 xf = ldh8(X + (size_t)(tok0 + rt * 16 + ln) * 256 + ks * 32 + quad * 8);
            #pragma unroll
            for (int ct = 0; ct < 4; ct++) acc[rt][ct] = MFMA(xf, wf[ct], acc[rt][ct]);
        }
        __syncthreads();
    }

    float bv[4];
    #pragma unroll
    for (int ct = 0; ct < 4; ct++) bv[ct] = bias[w * 64 + ct * 16 + ln];
    #pragma unroll
    for (int rt = 0; rt < 8; rt++)
        #pragma unroll
        for (int ct = 0; ct < 4; ct++)
            #pragma unroll
            for (int r = 0; r < 4; r++) {
                int tok = tok0 + rt * 16 + quad * 4 + r;
                int o = w * 64 + ct * 16 + ln;
                O[(size_t)tok * 256 + o] = f2h(acc[rt][ct][r] + bv[ct]);
            }
}

// ---------------- V conv1x1 GEMM: Xs -> V[o][tok] channel-major ------------
__launch_bounds__(256, 2)
__global__ void k_gemm_v(const u16* Xs, const u16* __restrict__ Wh2,
                         const float* __restrict__ bhp, u16* Vt) {
    int b = blockIdx.y, tok0 = blockIdx.x * 128;
    const u16* X = Xs + (size_t)b * 4096 * 256;
    __shared__ __align__(16) u16 wt[256 * 40];
    int t = threadIdx.x, w = t >> 6, lane = t & 63, ln = lane & 15, quad = lane >> 4;

    f32x4 acc[8][4];
    for (int i = 0; i < 8; i++)
        for (int j = 0; j < 4; j++) acc[i][j] = f32x4{0.f, 0.f, 0.f, 0.f};

    for (int ks = 0; ks < 8; ks++) {
        {
            const u16* wr = Wh2 + t * 256 + ks * 32;
            uint4 w0 = *(const uint4*)(wr + 0);
            uint4 w1 = *(const uint4*)(wr + 8);
            uint4 w2 = *(const uint4*)(wr + 16);
            uint4 w3 = *(const uint4*)(wr + 24);
            *(uint4*)(wt + t * 40 + 0)  = w0;
            *(uint4*)(wt + t * 40 + 8)  = w1;
            *(uint4*)(wt + t * 40 + 16) = w2;
            *(uint4*)(wt + t * 40 + 24) = w3;
        }
        __syncthreads();
        f16x8 wf[4];
        #pragma unroll
        for (int ct = 0; ct < 4; ct++)
            wf[ct] = ldh8(wt + (w * 64 + ct * 16 + ln) * 40 + quad * 8);
        #pragma unroll
        for (int rt = 0; rt < 8; rt++) {
            f16x8 xf = ldh8(X + (size_t)(tok0 + rt * 16 + ln) * 256 + ks * 32 + quad * 8);
            #pragma unroll
            for (int ct = 0; ct < 4; ct++) acc[rt][ct] = MFMA(wf[ct], xf, acc[rt][ct]);
        }
        __syncthreads();
    }

    u16* OV = Vt + (size_t)b * 256 * 4096;
    #pragma unroll
    for (int ct = 0; ct < 4; ct++)
        #pragma unroll
        for (int r = 0; r < 4; r++) {
            int o = w * 64 + ct * 16 + quad * 4 + r;
            float bb = bhp[o];
            #pragma unroll
            for (int rt = 0; rt < 8; rt++) {
                int tok = tok0 + rt * 16 + ln;
                OV[(size_t)o * 4096 + tok] = f2h(acc[rt][ct][r] + bb);
            }
        }
}

// ---------------- flash attention + fused AdaIN epilogue -------------------
// grid: (32 q-tiles of 128, 4 batch, 4 c-quarters) = 512 blocks = 2/CU.
// Wave owns 32 q-rows; m-tile 64 (two 32-row MFMA tiles) -> K-tile locality
// in L2 (R6-verified FETCH ~95MB). Softmax in-lane + one shfl_xor(32).
__launch_bounds__(256, 2)
__global__ void k_flash(const u16* __restrict__ Qt, const u16* __restrict__ Kt,
                        const u16* __restrict__ Vt,
                        const float* __restrict__ content, const float* __restrict__ cm,
                        const float* __restrict__ cr, float* __restrict__ out) {
    __shared__ __align__(16) char smem[79872];
    u16* Ks  = (u16*)smem;                   // [64 tok][264]  33792 B
    u16* Vs  = (u16*)(smem + 33792);         // [64 c][72]      9216 B
    u16* V2h = (u16*)(smem + 43008);         // [64 c][72]
    u16* V2l = (u16*)(smem + 52224);         // [64 c][72]
    int t = threadIdx.x, w = t >> 6, l = t & 63, lq = l & 31, h = l >> 5;
    u16* Psw = (u16*)(smem + 61440) + w * 2304;    // per-wave [32 q][72 m]

    int b = blockIdx.y, q0 = blockIdx.x * 128, coff = blockIdx.z * 64;

    // Q as B-operand fragments, pinned: col q = lq, k = h*8+j (+16ks)
    f16x8 qf[16];
    {
        const u16* qp = Qt + ((size_t)b * 4096 + q0 + w * 32 + lq) * 256 + h * 8;
        #pragma unroll
        for (int ks = 0; ks < 16; ks++) qf[ks] = ldh8(qp + ks * 16);
    }

    f32x16 am[2], aq[2];
    #pragma unroll
    for (int i = 0; i < 16; i++) { am[0][i] = 0.f; am[1][i] = 0.f; aq[0][i] = 0.f; aq[1][i] = 0.f; }
    float mrow = -1e30f, lrow = 0.f;

    const u16* Kg = Kt + (size_t)b * 4096 * 256;
    const u16* Vg = Vt + ((size_t)b * 256 + coff) * 4096;

    for (int it = 0; it < 64; it++) {
        int m0 = it * 64;
        // stage K tile [64 tok][256 c]
        #pragma unroll
        for (int i = 0; i < 8; i++) {
            int e = i * 256 + t, row = e >> 5, c16 = e & 31;
            *(uint4*)(Ks + row * 264 + c16 * 8) =
                *(const uint4*)(Kg + (size_t)(m0 + row) * 256 + c16 * 8);
        }
        // stage V tile [64 c][64 m] + exact Dekker hi/lo split of v^2 (pk f16)
        #pragma unroll
        for (int i = 0; i < 2; i++) {
            int e = i * 256 + t, row = e >> 3, m16 = e & 7;
            uint4 v = *(const uint4*)(Vg + (size_t)row * 4096 + m0 + m16 * 8);
            *(uint4*)(Vs + row * 72 + m16 * 8) = v;
            f16x8 vv = __builtin_bit_cast(f16x8, v);
            f16x8 qh = vv * vv;                                  // round(v^2)
            f16x8 ql = __builtin_elementwise_fma(vv, vv, -qh);   // exact remainder
            *(uint4*)(V2h + row * 72 + m16 * 8) = __builtin_bit_cast(uint4, qh);
            *(uint4*)(V2l + row * 72 + m16 * 8) = __builtin_bit_cast(uint4, ql);
        }
        __syncthreads();

        // S^T[m][q] = K * Q^T   (two 32-row m-tiles)
        f32x16 s0, s1;
        #pragma unroll
        for (int i = 0; i < 16; i++) { s0[i] = 0.f; s1[i] = 0.f; }
        #pragma unroll
        for (int ks = 0; ks < 16; ks++) {
            f16x8 k0 = ldh8(Ks + lq * 264 + ks * 16 + h * 8);
            s0 = MFMA32(k0, qf[ks], s0);
            f16x8 k1 = ldh8(Ks + (32 + lq) * 264 + ks * 16 + h * 8);
            s1 = MFMA32(k1, qf[ks], s1);
        }

        // online softmax over m: in-lane (32 vals) + one shfl_xor(32)
        float mt = s0[0];
        #pragma unroll
        for (int r = 1; r < 16; r++) mt = fmaxf(mt, s0[r]);
        #pragma unroll
        for (int r = 0; r < 16; r++) mt = fmaxf(mt, s1[r]);
        mt = fmaxf(mt, __shfl_xor(mt, 32));
        float mn = fmaxf(mrow, mt);
        float al = EXP2((mrow - mn) * L2E);
        mrow = mn;
        float base = mn * L2E;
        float rs = 0.f;
        #pragma unroll
        for (int r = 0; r < 16; r++) {
            float p0 = (float)(_Float16)EXP2(__builtin_fmaf(s0[r], L2E, -base));
            float p1 = (float)(_Float16)EXP2(__builtin_fmaf(s1[r], L2E, -base));
            s0[r] = p0; s1[r] = p1;
            rs += p0 + p1;
        }
        rs += __shfl_xor(rs, 32);
        lrow = lrow * al + rs;

        // rescale accumulators; alpha of q broadcast via shfl (lane q holds it)
        #pragma unroll
        for (int r = 0; r < 16; r++) {
            float sc = __shfl(al, 8 * (r >> 2) + 4 * h + (r & 3));
            am[0][r] *= sc; am[1][r] *= sc;
            aq[0][r] *= sc; aq[1][r] *= sc;
        }

        // P -> Psw[q = lq][m], packed 4 consecutive m per b64 write
        #pragma unroll
        for (int mt2 = 0; mt2 < 2; mt2++)
            #pragma unroll
            for (int rq = 0; rq < 4; rq++) {
                float e0 = mt2 ? s1[4 * rq + 0] : s0[4 * rq + 0];
                float e1 = mt2 ? s1[4 * rq + 1] : s0[4 * rq + 1];
                float e2 = mt2 ? s1[4 * rq + 2] : s0[4 * rq + 2];
                float e3 = mt2 ? s1[4 * rq + 3] : s0[4 * rq + 3];
                uint2 pk;
                pk.x = (u32)f2h(e0) | ((u32)f2h(e1) << 16);
                pk.y = (u32)f2h(e2) | ((u32)f2h(e3) << 16);
                *(uint2*)(Psw + lq * 72 + mt2 * 32 + rq * 8 + h * 4) = pk;
            }

        // PV: D[q][c] += P*V (am), P*V2h + P*V2l (aq); same-wave LDS RAW
        #pragma unroll
        for (int ks = 0; ks < 4; ks++) {
            f16x8 pf = ldh8(Psw + lq * 72 + ks * 16 + h * 8);
            #pragma unroll
            for (int ct = 0; ct < 2; ct++) {
                int vo = (ct * 32 + lq) * 72 + ks * 16 + h * 8;
                am[ct] = MFMA32(pf, ldh8(Vs + vo), am[ct]);
                aq[ct] = MFMA32(pf, ldh8(V2h + vo), aq[ct]);
                aq[ct] = MFMA32(pf, ldh8(V2l + vo), aq[ct]);
            }
        }
        __syncthreads();
    }

    // ---------------- epilogue: out = std * norm(content) + mean ----------
    float inv = 1.0f / lrow;
    float iv[16];
    #pragma unroll
    for (int r = 0; r < 16; r++) iv[r] = __shfl(inv, (r & 3) + 8 * (r >> 2) + 4 * h);
    float* Ms = (float*)smem;                  // [64 c][132 q] f32
    float* Ss = (float*)(smem + 33792);
    #pragma unroll
    for (int ct = 0; ct < 2; ct++)
        #pragma unroll
        for (int rq = 0; rq < 4; rq++) {
            f32x4 mv, sv;
            #pragma unroll
            for (int j = 0; j < 4; j++) {
                int r = 4 * rq + j;
                float mean = am[ct][r] * iv[r];
                float ex2 = aq[ct][r] * iv[r];
                float var = ex2 - mean * mean;
                mv[j] = mean;
                sv[j] = sqrtf(fmaxf(var, 0.f));
            }
            int c = ct * 32 + lq;
            int qloc = w * 32 + 8 * rq + 4 * h;
            *(f32x4*)(Ms + c * 132 + qloc) = mv;
            *(f32x4*)(Ss + c * 132 + qloc) = sv;
        }
    __syncthreads();
    #pragma unroll
    for (int pass = 0; pass < 8; pass++) {
        int c = pass * 8 + (t >> 5);
        int qloc = (t & 31) * 4;
        f32x4 mv = *(const f32x4*)(Ms + c * 132 + qloc);
        f32x4 sv = *(const f32x4*)(Ss + c * 132 + qloc);
        int gc = coff + c;
        size_t basei = ((size_t)b * 256 + gc) * 4096 + q0 + qloc;
        float4 cv = *(const float4*)(content + basei);
        float cmv = cm[b * 256 + gc], crv = cr[b * 256 + gc];
        float4 o;
        o.x = sv[0] * ((cv.x - cmv) * crv) + mv[0];
        o.y = sv[1] * ((cv.y - cmv) * crv) + mv[1];
        o.z = sv[2] * ((cv.z - cmv) * crv) + mv[2];
        o.w = sv[3] * ((cv.w - cmv) * crv) + mv[3];
        *(float4*)(out + basei) = o;
    }
}

// ---------------------------------------------------------------------------
extern "C" void kernel_launch(void* const* d_in, const int* in_sizes, int n_in,
                              void* d_out, int out_size, void* d_ws, size_t ws_size,
                              hipStream_t stream) {
    const float* content = (const float*)d_in[0];
    const float* style   = (const float*)d_in[1];
    const float* ckey    = (const float*)d_in[2];
    const float* skey    = (const float*)d_in[3];
    const float* Wf      = (const float*)d_in[4];
    const float* bfp     = (const float*)d_in[5];
    const float* Wg      = (const float*)d_in[6];
    const float* bgp     = (const float*)d_in[7];
    const float* Wh      = (const float*)d_in[8];
    const float* bhp     = (const float*)d_in[9];
    float* out = (float*)d_out;
    char* ws = (char*)d_ws;

    float* cm = (float*)(ws + 0);               //  4 KiB
    float* cr = (float*)(ws + 4096);            //  4 KiB
    u16*   Wb = (u16*)(ws + 8192);              //  384 KiB
    u16*   A  = (u16*)(ws + 1048576);           //  8 MiB: Xs -> Qt
    u16*   Bv = (u16*)(ws + 9437184);           //  8 MiB: Vt [c][tok]
    u16*   Cc = (u16*)(ws + 17825792);          //  8 MiB: Xk -> Kt
    u16*   Xq = (u16*)d_out;                    //  8 MiB scratch inside out

    k_stats<<<dim3(1024), 256, 0, stream>>>(content, cm, cr);
    k_prep<<<dim3(64, 4, 15), 256, 0, stream>>>(style, ckey, skey, Wf, Wg, Wh,
                                                A, Xq, Cc, Wb);
    k_gemm_v<<<dim3(32, 4), 256, 0, stream>>>(A, Wb + 2 * 65536, bhp, Bv);
    k_gemm_qk<<<dim3(32, 4, 2), 256, 0, stream>>>(Xq, A, Cc, Wb, bfp, bgp);
    k_flash<<<dim3(32, 4, 4), 256, 0, stream>>>(A, Cc, Bv, content, cm, cr, out);
}

// Round 9
// 417.972 us; speedup vs baseline: 2.6394x; 1.0069x over previous
//
#include <hip/hip_runtime.h>

// ---------------------------------------------------------------------------
// ASA (AdaAttN-style) fused pipeline for MI355X / gfx950
// B=4, C=256, H=W=64 -> N=M=4096 tokens.
//
// R9 (on R8's verified structure):
//  * k_flash: V^2 hi/lo computed IN-REGISTER from the V B-fragment
//    (squaring commutes with fragment extraction; pk_mul + pk_fma, RTNE
//    bit-identical to staged version). Deletes V2h/V2l LDS buffers,
//    2/3 of V staging writes, 16/24 PV fragment reads per wave-iter.
//  * prefix: all 3 conv GEMMs in ONE launch (384 blocks); style/ckey
//    transposed into d_out's two 8-MiB halves (scratch, dead before
//    k_flash overwrites out). 4 launches total.
//
//  ws + 0      : cm [1024] f32      ws + 4096  : cr [1024] f32
//  ws + 8192   : Wb [3*65536] fp16
//  ws + 1 MiB  : A  8 MiB fp16  Qt
//  ws + 9 MiB  : Bv 8 MiB fp16  Vt [c][tok]
//  ws + 17 MiB : Cc 8 MiB fp16  Xk -> Kt (in-place)
//  d_out lo/hi : X1 (style^T), X2 (ckey^T) scratch
// ---------------------------------------------------------------------------

typedef unsigned int u32;
typedef unsigned short u16;
typedef _Float16 f16x8 __attribute__((ext_vector_type(8)));
typedef float f32x4 __attribute__((ext_vector_type(4)));
typedef float f32x16 __attribute__((ext_vector_type(16)));

#define L2E 1.44269504088896340736f
#define MFMA(a, b, c) __builtin_amdgcn_mfma_f32_16x16x32_f16(a, b, c, 0, 0, 0)
#define MFMA32(a, b, c) __builtin_amdgcn_mfma_f32_32x32x16_f16(a, b, c, 0, 0, 0)
#define EXP2(x) __builtin_amdgcn_exp2f(x)

__device__ __forceinline__ u16 h_bits(_Float16 h) { return __builtin_bit_cast(u16, h); }
__device__ __forceinline__ u16 f2h(float f) { return h_bits((_Float16)f); }

__device__ __forceinline__ f16x8 ldh8(const u16* p) {
    uint4 v = *(const uint4*)p;
    return __builtin_bit_cast(f16x8, v);
}

// ---------------- content stats: mean & rstd per (b,c) ---------------------
__global__ void k_stats(const float* __restrict__ content,
                        float* __restrict__ cm, float* __restrict__ cr) {
    int blk = blockIdx.x;                       // 0..1023 = b*256+c
    const float* p = content + (size_t)blk * 4096;
    int t = threadIdx.x;
    float s = 0.f, ss = 0.f;
    for (int i = 0; i < 4; i++) {
        float4 v = *(const float4*)(p + (i * 256 + t) * 4);
        s  += (v.x + v.y) + (v.z + v.w);
        ss += (v.x * v.x + v.y * v.y) + (v.z * v.z + v.w * v.w);
    }
    for (int d = 32; d >= 1; d >>= 1) { s += __shfl_xor(s, d); ss += __shfl_xor(ss, d); }
    __shared__ __align__(16) float as[4], ass[4];
    int w = t >> 6;
    if ((t & 63) == 0) { as[w] = s; ass[w] = ss; }
    __syncthreads();
    if (t == 0) {
        s  = (as[0] + as[1]) + (as[2] + as[3]);
        ss = (ass[0] + ass[1]) + (ass[2] + ass[3]);
        float mean = s * (1.0f / 4096.0f);
        float var = (ss - s * mean) * (1.0f / 4095.0f);   // unbiased (ddof=1)
        cm[blk] = mean;
        cr[blk] = rsqrtf(var + 1e-5f);
    }
}

// ---------------- prep: 3 transposes + weight cvt in ONE launch ------------
// z 0..3: style->X1 ; 4..7: ckey->X2 ; 8..11: skey->Cc ; 12..14: weights
__global__ void k_prep(const float* __restrict__ style, const float* __restrict__ ckey,
                       const float* __restrict__ skey,
                       const float* __restrict__ Wf, const float* __restrict__ Wg,
                       const float* __restrict__ Wh,
                       u16* __restrict__ X1, u16* __restrict__ X2, u16* __restrict__ Cc,
                       u16* __restrict__ Wb) {
    int z = blockIdx.z, t = threadIdx.x;
    if (z >= 12) {
        if (blockIdx.y != 0) return;
        int m = z - 12;
        const float* src = (m == 0) ? Wf : ((m == 1) ? Wg : Wh);
        u16* dst = Wb + m * 65536;
        int i = (blockIdx.x * 256 + t) * 4;
        float4 v = *(const float4*)(src + i);
        ushort4 o;
        o.x = f2h(v.x); o.y = f2h(v.y); o.z = f2h(v.z); o.w = f2h(v.w);
        *(ushort4*)(dst + i) = o;
        return;
    }
    int tensor = z >> 2, b = z & 3;
    const float* src = ((tensor == 0) ? style : ((tensor == 1) ? ckey : skey))
                       + (size_t)b * 256 * 4096;
    u16* dst = ((tensor == 0) ? X1 : ((tensor == 1) ? X2 : Cc)) + (size_t)b * 4096 * 256;
    int c0 = blockIdx.y * 64, t0 = blockIdx.x * 64;
    __shared__ __align__(16) float ls[64][65];
    int tr = t >> 4, tc = t & 15;
    for (int i = 0; i < 4; i++) {
        int c_off = i * 16 + tr;
        float4 v = *(const float4*)(src + (size_t)(c0 + c_off) * 4096 + t0 + tc * 4);
        ls[tc * 4 + 0][c_off] = v.x;
        ls[tc * 4 + 1][c_off] = v.y;
        ls[tc * 4 + 2][c_off] = v.z;
        ls[tc * 4 + 3][c_off] = v.w;
    }
    __syncthreads();
    for (int i = 0; i < 4; i++) {
        int tokrow = i * 16 + tr;
        ushort4 o;
        o.x = f2h(ls[tokrow][tc * 4 + 0]);
        o.y = f2h(ls[tokrow][tc * 4 + 1]);
        o.z = f2h(ls[tokrow][tc * 4 + 2]);
        o.w = f2h(ls[tokrow][tc * 4 + 3]);
        *(ushort4*)(dst + (size_t)(t0 + tokrow) * 256 + c0 + tc * 4) = o;
    }
}

// ---------------- all three conv1x1 GEMMs, one launch -----------------------
// mode 0: Q = X2*Wf^T + bf -> A (token-major)
// mode 1: K = Cc*Wg^T + bg -> Cc (in-place, token-major)
// mode 2: V = Wh*X1 + bh   -> Bv (channel-major)
__launch_bounds__(256, 2)
__global__ void k_gemm(const u16* X1, const u16* X2, u16* Cc,
                       u16* A, u16* Bv, const u16* __restrict__ Wb,
                       const float* __restrict__ bfp, const float* __restrict__ bgp,
                       const float* __restrict__ bhp) {
    int mode = blockIdx.z, b = blockIdx.y, tok0 = blockIdx.x * 128;
    const u16* X = ((mode == 0) ? X2 : ((mode == 1) ? (const u16*)Cc : X1))
                   + (size_t)b * 4096 * 256;
    const u16* W = Wb + mode * 65536;
    const float* bias = (mode == 0) ? bfp : ((mode == 1) ? bgp : bhp);
    __shared__ __align__(16) u16 wt[256 * 40];
    int t = threadIdx.x, w = t >> 6, lane = t & 63, ln = lane & 15, quad = lane >> 4;

    f32x4 acc[8][4];
    for (int i = 0; i < 8; i++)
        for (int j = 0; j < 4; j++) acc[i][j] = f32x4{0.f, 0.f, 0.f, 0.f};

    for (int ks = 0; ks < 8; ks++) {
        {   // stage W[o = t][ks*32 .. +32) -> LDS : full 64 B per row
            const u16* wr = W + t * 256 + ks * 32;
            uint4 w0 = *(const uint4*)(wr + 0);
            uint4 w1 = *(const uint4*)(wr + 8);
            uint4 w2 = *(const uint4*)(wr + 16);
            uint4 w3 = *(const uint4*)(wr + 24);
            *(uint4*)(wt + t * 40 + 0)  = w0;
            *(uint4*)(wt + t * 40 + 8)  = w1;
            *(uint4*)(wt + t * 40 + 16) = w2;
            *(uint4*)(wt + t * 40 + 24) = w3;
        }
        __syncthreads();
        f16x8 wf[4];
        #pragma unroll
        for (int ct = 0; ct < 4; ct++)
            wf[ct] = ldh8(wt + (w * 64 + ct * 16 + ln) * 40 + quad * 8);
        #pragma unroll
        for (int rt = 0; rt < 8; rt++) {
            f16x8 xf = ldh8(X + (size_t)(tok0 + rt * 16 + ln) * 256 + ks * 32 + quad * 8);
            if (mode < 2) {
                #pragma unroll
                for (int ct = 0; ct < 4; ct++) acc[rt][ct] = MFMA(xf, wf[ct], acc[rt][ct]);
            } else {
                #pragma unroll
                for (int ct = 0; ct < 4; ct++) acc[rt][ct] = MFMA(wf[ct], xf, acc[rt][ct]);
            }
        }
        __syncthreads();
    }

    if (mode < 2) {
        u16* O = ((mode == 0) ? A : Cc) + (size_t)b * 4096 * 256;
        float bv[4];
        #pragma unroll
        for (int ct = 0; ct < 4; ct++) bv[ct] = bias[w * 64 + ct * 16 + ln];
        #pragma unroll
        for (int rt = 0; rt < 8; rt++)
            #pragma unroll
            for (int ct = 0; ct < 4; ct++)
                #pragma unroll
                for (int r = 0; r < 4; r++) {
                    int tok = tok0 + rt * 16 + quad * 4 + r;
                    int o = w * 64 + ct * 16 + ln;
                    O[(size_t)tok * 256 + o] = f2h(acc[rt][ct][r] + bv[ct]);
                }
    } else {
        u16* OV = Bv + (size_t)b * 256 * 4096;
        #pragma unroll
        for (int ct = 0; ct < 4; ct++)
            #pragma unroll
            for (int r = 0; r < 4; r++) {
                int o = w * 64 + ct * 16 + quad * 4 + r;
                float bb = bias[o];
                #pragma unroll
                for (int rt = 0; rt < 8; rt++) {
                    int tok = tok0 + rt * 16 + ln;
                    OV[(size_t)o * 4096 + tok] = f2h(acc[rt][ct][r] + bb);
                }
            }
    }
}

// ---------------- flash attention + fused AdaIN epilogue -------------------
// grid: (32 q-tiles of 128, 4 batch, 4 c-quarters) = 512 blocks = 2/CU.
// Wave owns 32 q-rows; m-tile 64. V^2 hi/lo from the V fragment in-register.
__launch_bounds__(256, 2)
__global__ void k_flash(const u16* __restrict__ Qt, const u16* __restrict__ Kt,
                        const u16* __restrict__ Vt,
                        const float* __restrict__ content, const float* __restrict__ cm,
                        const float* __restrict__ cr, float* __restrict__ out) {
    __shared__ __align__(16) char smem[67584];
    u16* Ks = (u16*)smem;                    // [64 tok][264]  33792 B
    u16* Vs = (u16*)(smem + 33792);          // [64 c][72]      9216 B
    int t = threadIdx.x, w = t >> 6, l = t & 63, lq = l & 31, h = l >> 5;
    u16* Psw = (u16*)(smem + 43008) + w * 2304;    // per-wave [32 q][72 m]

    int b = blockIdx.y, q0 = blockIdx.x * 128, coff = blockIdx.z * 64;

    // Q as B-operand fragments, pinned: col q = lq, k = h*8+j (+16ks)
    f16x8 qf[16];
    {
        const u16* qp = Qt + ((size_t)b * 4096 + q0 + w * 32 + lq) * 256 + h * 8;
        #pragma unroll
        for (int ks = 0; ks < 16; ks++) qf[ks] = ldh8(qp + ks * 16);
    }

    f32x16 am[2], aq[2];
    #pragma unroll
    for (int i = 0; i < 16; i++) { am[0][i] = 0.f; am[1][i] = 0.f; aq[0][i] = 0.f; aq[1][i] = 0.f; }
    float mrow = -1e30f, lrow = 0.f;

    const u16* Kg = Kt + (size_t)b * 4096 * 256;
    const u16* Vg = Vt + ((size_t)b * 256 + coff) * 4096;

    for (int it = 0; it < 64; it++) {
        int m0 = it * 64;
        // stage K tile [64 tok][256 c]
        #pragma unroll
        for (int i = 0; i < 8; i++) {
            int e = i * 256 + t, row = e >> 5, c16 = e & 31;
            *(uint4*)(Ks + row * 264 + c16 * 8) =
                *(const uint4*)(Kg + (size_t)(m0 + row) * 256 + c16 * 8);
        }
        // stage V tile [64 c][64 m] (no V^2 buffers)
        #pragma unroll
        for (int i = 0; i < 2; i++) {
            int e = i * 256 + t, row = e >> 3, m16 = e & 7;
            *(uint4*)(Vs + row * 72 + m16 * 8) =
                *(const uint4*)(Vg + (size_t)row * 4096 + m0 + m16 * 8);
        }
        __syncthreads();

        // S^T[m][q] = K * Q^T   (two 32-row m-tiles)
        f32x16 s0, s1;
        #pragma unroll
        for (int i = 0; i < 16; i++) { s0[i] = 0.f; s1[i] = 0.f; }
        #pragma unroll
        for (int ks = 0; ks < 16; ks++) {
            f16x8 k0 = ldh8(Ks + lq * 264 + ks * 16 + h * 8);
            s0 = MFMA32(k0, qf[ks], s0);
            f16x8 k1 = ldh8(Ks + (32 + lq) * 264 + ks * 16 + h * 8);
            s1 = MFMA32(k1, qf[ks], s1);
        }

        // online softmax over m: in-lane (32 vals) + one shfl_xor(32)
        float mt = s0[0];
        #pragma unroll
        for (int r = 1; r < 16; r++) mt = fmaxf(mt, s0[r]);
        #pragma unroll
        for (int r = 0; r < 16; r++) mt = fmaxf(mt, s1[r]);
        mt = fmaxf(mt, __shfl_xor(mt, 32));
        float mn = fmaxf(mrow, mt);
        float al = EXP2((mrow - mn) * L2E);
        mrow = mn;
        float base = mn * L2E;
        float rs = 0.f;
        #pragma unroll
        for (int r = 0; r < 16; r++) {
            float p0 = (float)(_Float16)EXP2(__builtin_fmaf(s0[r], L2E, -base));
            float p1 = (float)(_Float16)EXP2(__builtin_fmaf(s1[r], L2E, -base));
            s0[r] = p0; s1[r] = p1;
            rs += p0 + p1;
        }
        rs += __shfl_xor(rs, 32);
        lrow = lrow * al + rs;

        // rescale accumulators; alpha of q broadcast via shfl (lane q holds it)
        #pragma unroll
        for (int r = 0; r < 16; r++) {
            float sc = __shfl(al, 8 * (r >> 2) + 4 * h + (r & 3));
            am[0][r] *= sc; am[1][r] *= sc;
            aq[0][r] *= sc; aq[1][r] *= sc;
        }

        // P -> Psw[q = lq][m], packed 4 consecutive m per b64 write
        #pragma unroll
        for (int mt2 = 0; mt2 < 2; mt2++)
            #pragma unroll
            for (int rq = 0; rq < 4; rq++) {
                float e0 = mt2 ? s1[4 * rq + 0] : s0[4 * rq + 0];
                float e1 = mt2 ? s1[4 * rq + 1] : s0[4 * rq + 1];
                float e2 = mt2 ? s1[4 * rq + 2] : s0[4 * rq + 2];
                float e3 = mt2 ? s1[4 * rq + 3] : s0[4 * rq + 3];
                uint2 pk;
                pk.x = (u32)f2h(e0) | ((u32)f2h(e1) << 16);
                pk.y = (u32)f2h(e2) | ((u32)f2h(e3) << 16);
                *(uint2*)(Psw + lq * 72 + mt2 * 32 + rq * 8 + h * 4) = pk;
            }

        // PV: D[q][c] += P*V (am), P*(v^2 hi) + P*(v^2 lo) (aq).
        // v^2 hi/lo computed in-register from the V fragment (exact Dekker).
        #pragma unroll
        for (int ks = 0; ks < 4; ks++) {
            f16x8 pf = ldh8(Psw + lq * 72 + ks * 16 + h * 8);
            #pragma unroll
            for (int ct = 0; ct < 2; ct++) {
                f16x8 vf = ldh8(Vs + (ct * 32 + lq) * 72 + ks * 16 + h * 8);
                am[ct] = MFMA32(pf, vf, am[ct]);
                f16x8 vh = vf * vf;                                  // round(v^2)
                f16x8 vl = __builtin_elementwise_fma(vf, vf, -vh);   // exact residual
                aq[ct] = MFMA32(pf, vh, aq[ct]);
                aq[ct] = MFMA32(pf, vl, aq[ct]);
            }
        }
        __syncthreads();
    }

    // ---------------- epilogue: out = std * norm(content) + mean ----------
    float inv = 1.0f / lrow;
    float iv[16];
    #pragma unroll
    for (int r = 0; r < 16; r++) iv[r] = __shfl(inv, (r & 3) + 8 * (r >> 2) + 4 * h);
    float* Ms = (float*)smem;                  // [64 c][132 q] f32
    float* Ss = (float*)(smem + 33792);
    #pragma unroll
    for (int ct = 0; ct < 2; ct++)
        #pragma unroll
        for (int rq = 0; rq < 4; rq++) {
            f32x4 mv, sv;
            #pragma unroll
            for (int j = 0; j < 4; j++) {
                int r = 4 * rq + j;
                float mean = am[ct][r] * iv[r];
                float ex2 = aq[ct][r] * iv[r];
                float var = ex2 - mean * mean;
                mv[j] = mean;
                sv[j] = sqrtf(fmaxf(var, 0.f));
            }
            int c = ct * 32 + lq;
            int qloc = w * 32 + 8 * rq + 4 * h;
            *(f32x4*)(Ms + c * 132 + qloc) = mv;
            *(f32x4*)(Ss + c * 132 + qloc) = sv;
        }
    __syncthreads();
    #pragma unroll
    for (int pass = 0; pass < 8; pass++) {
        int c = pass * 8 + (t >> 5);
        int qloc = (t & 31) * 4;
        f32x4 mv = *(const f32x4*)(Ms + c * 132 + qloc);
        f32x4 sv = *(const f32x4*)(Ss + c * 132 + qloc);
        int gc = coff + c;
        size_t basei = ((size_t)b * 256 + gc) * 4096 + q0 + qloc;
        float4 cv = *(const float4*)(content + basei);
        float cmv = cm[b * 256 + gc], crv = cr[b * 256 + gc];
        float4 o;
        o.x = sv[0] * ((cv.x - cmv) * crv) + mv[0];
        o.y = sv[1] * ((cv.y - cmv) * crv) + mv[1];
        o.z = sv[2] * ((cv.z - cmv) * crv) + mv[2];
        o.w = sv[3] * ((cv.w - cmv) * crv) + mv[3];
        *(float4*)(out + basei) = o;
    }
}

// ---------------------------------------------------------------------------
extern "C" void kernel_launch(void* const* d_in, const int* in_sizes, int n_in,
                              void* d_out, int out_size, void* d_ws, size_t ws_size,
                              hipStream_t stream) {
    const float* content = (const float*)d_in[0];
    const float* style   = (const float*)d_in[1];
    const float* ckey    = (const float*)d_in[2];
    const float* skey    = (const float*)d_in[3];
    const float* Wf      = (const float*)d_in[4];
    const float* bfp     = (const float*)d_in[5];
    const float* Wg      = (const float*)d_in[6];
    const float* bgp     = (const float*)d_in[7];
    const float* Wh      = (const float*)d_in[8];
    const float* bhp     = (const float*)d_in[9];
    float* out = (float*)d_out;
    char* ws = (char*)d_ws;

    float* cm = (float*)(ws + 0);               //  4 KiB
    float* cr = (float*)(ws + 4096);            //  4 KiB
    u16*   Wb = (u16*)(ws + 8192);              //  384 KiB
    u16*   A  = (u16*)(ws + 1048576);           //  8 MiB: Qt
    u16*   Bv = (u16*)(ws + 9437184);           //  8 MiB: Vt [c][tok]
    u16*   Cc = (u16*)(ws + 17825792);          //  8 MiB: Xk -> Kt
    u16*   X1 = (u16*)d_out;                    //  8 MiB scratch (style^T)
    u16*   X2 = (u16*)d_out + 4194304;          //  8 MiB scratch (ckey^T)

    k_stats<<<dim3(1024), 256, 0, stream>>>(content, cm, cr);
    k_prep<<<dim3(64, 4, 15), 256, 0, stream>>>(style, ckey, skey, Wf, Wg, Wh,
                                                X1, X2, Cc, Wb);
    k_gemm<<<dim3(32, 4, 3), 256, 0, stream>>>(X1, X2, Cc, A, Bv, Wb, bfp, bgp, bhp);
    k_flash<<<dim3(32, 4, 4), 256, 0, stream>>>(A, Cc, Bv, content, cm, cr, out);
}